// Round 19
// baseline (517.324 us; speedup 1.0000x reference)
//
#include <hip/hip_runtime.h>
#include <stdint.h>

#define BB 4096
#define TT 512
#define HH 32
#define SS 4

__device__ __forceinline__ float fast_sigm(float a) {
  return __builtin_amdgcn_rcpf(1.0f + __expf(-a));      // v_exp + v_rcp
}
__device__ __forceinline__ float fast_tanh(float y) {
  return 1.0f - 2.0f * __builtin_amdgcn_rcpf(__expf(2.0f * y) + 1.0f);
}

// pack two f32 -> f16 pair (validated r17, absmax 3.9e-3 end-to-end)
#define PKH(dst, lo, hi)                                                       \
  asm volatile("v_cvt_pkrtz_f16_f32 %0, %1, %2" : "=v"(dst) : "v"(lo), "v"(hi))
// mixed FMA: acc(f32) += f16half(w) * f32(h)  (validated r17)
#define MIXLO(acc, w, h)                                                       \
  asm("v_fma_mix_f32 %0, %1, %2, %0 op_sel:[0,0,0] op_sel_hi:[1,0,0]"          \
      : "+v"(acc) : "v"(w), "v"(h))
#define MIXHI(acc, w, h)                                                       \
  asm("v_fma_mix_f32 %0, %1, %2, %0 op_sel:[1,0,0] op_sel_hi:[1,0,0]"          \
      : "+v"(acc) : "v"(w), "v"(h))
// acc += Wpair[2c],Wpair[2c+1] . quad
#define MIXQ(acc, W, c, q)                                                     \
  MIXLO(acc, W[2*(c)], (q).x); MIXHI(acc, W[2*(c)], (q).y);                    \
  MIXLO(acc, W[2*(c)+1], (q).z); MIXHI(acc, W[2*(c)+1], (q).w)

// Gate-split design: wave = 2 batches (A=grp0's, B=grp1's). Group 0 lane j owns
// w_r[j], w_z[j]; group 1 owns w_n[j], w_proj[j&3] — 2 rows = 32 f16-pair regs
// per lane, BY CONSTRUCTION under the allocator's spill threshold. Each group
// dots its 2 rows against BOTH batches' h (128 fma_mix, uniform); 4 shfl_xor(32)
// exchanges route (r,z)<->(n,xn,proj) so grp0 finalizes A, grp1 finalizes B.
// h broadcast via per-batch LDS rows (group-uniform addresses ~free, r11 PMC
// model); proj is a full K=32 dot (no butterfly). Zero weight memory traffic.
__global__ void __launch_bounds__(256, 2)
gru_kernel(const float* __restrict__ x, const float* __restrict__ h0,
           const float* __restrict__ w_ih, const float* __restrict__ w_hh,
           const float* __restrict__ b_ih, const float* __restrict__ b_hh,
           const float* __restrict__ w_proj, const float* __restrict__ b_proj,
           float* __restrict__ out) {
  const int tid  = threadIdx.x;
  const int wid  = tid >> 6;        // wave 0..3
  const int lane = tid & 63;
  const int j    = lane & 31;       // row index within gate
  const int grp  = lane >> 5;       // 0: finalizes batch A; 1: batch B
  const int rowF = wid * 2 + grp;   // this lane's FINAL batch LDS row
  const int bF   = blockIdx.x * 8 + rowF;

  __shared__ float hl[8][36];       // h rows (144B stride, conflict-free r5+)
  float* lrowF = &hl[rowF][0];
  const float4* lrowX = (const float4*)lrowF;            // own batch
  const float4* lrowY = (const float4*)&hl[wid * 2 + (1 - grp)][0];  // other

  // ---- weights: 2 rows of 32, f16-packed (32 regs) ----
  uint32_t W0[16], W1[16], XW0[2], XW1[2];
  {
    const float4* p0 = (const float4*)(grp ? (w_hh + (64 + j) * HH)
                                           : (w_hh + j * HH));
    const float4* p1 = (const float4*)(grp ? (w_proj + (j & 3) * HH)
                                           : (w_hh + (32 + j) * HH));
#pragma unroll
    for (int c = 0; c < 8; ++c) {
      const float4 q0 = p0[c], q1 = p1[c];
      PKH(W0[2*c], q0.x, q0.y); PKH(W0[2*c+1], q0.z, q0.w);
      PKH(W1[2*c], q1.x, q1.y); PKH(W1[2*c+1], q1.z, q1.w);
    }
    const float4 qx0 = *(const float4*)(grp ? (w_ih + (64 + j) * 4)
                                            : (w_ih + j * 4));
    const float4 qx1 = *(const float4*)(grp ? (w_ih + (64 + j) * 4)
                                            : (w_ih + (32 + j) * 4));
    PKH(XW0[0], qx0.x, qx0.y); PKH(XW0[1], qx0.z, qx0.w);
    PKH(XW1[0], qx1.x, qx1.y); PKH(XW1[1], qx1.z, qx1.w);
  }

  // ---- per-lane bias inits ----
  const float bx0 = grp ? b_ih[64 + j] : b_ih[j];        // xn / xr init
  const float bx1 = grp ? 0.0f         : b_ih[32 + j];   // (junk) / xz init
  const float bh0 = grp ? b_hh[64 + j] : b_hh[j];        // nh / hr init
  const float bh1 = grp ? 0.0f         : b_hh[32 + j];   // proj / hz init
  const float bp  = b_proj[j & 3];

  float h_self = h0[(size_t)bF * HH + j];
  lrowF[j] = h_self;                // wave inits its own 2 rows (same-wave DS)

  const float4* xF = (const float4*)(x + (size_t)bF * TT * 4);
  const float4* xO = (const float4*)(x + (size_t)(bF ^ 1) * TT * 4);
  float* outF = out + (size_t)bF * TT * SS;

  for (int t = 0; t <= TT; ++t) {
    const int tc = (t < TT) ? t : (TT - 1);
    const float4 xvF = xF[tc];
    const float4 xvO = xO[tc];

    // h quads, both batches (group-uniform addresses -> broadcast reads)
    float4 hx[8], hy[8];
#pragma unroll
    for (int c = 0; c < 8; ++c) { hx[c] = lrowX[c]; hy[c] = lrowY[c]; }

    // x dots (16 fma_mix; grp1's XW1 dots are discarded junk)
    float xa_x0 = bx0, xa_y0 = bx0, xa_x1 = bx1, xa_y1 = bx1;
    MIXLO(xa_x0, XW0[0], xvF.x); MIXHI(xa_x0, XW0[0], xvF.y);
    MIXLO(xa_x0, XW0[1], xvF.z); MIXHI(xa_x0, XW0[1], xvF.w);
    MIXLO(xa_y0, XW0[0], xvO.x); MIXHI(xa_y0, XW0[0], xvO.y);
    MIXLO(xa_y0, XW0[1], xvO.z); MIXHI(xa_y0, XW0[1], xvO.w);
    MIXLO(xa_x1, XW1[0], xvF.x); MIXHI(xa_x1, XW1[0], xvF.y);
    MIXLO(xa_x1, XW1[1], xvF.z); MIXHI(xa_x1, XW1[1], xvF.w);
    MIXLO(xa_y1, XW1[0], xvO.x); MIXHI(xa_y1, XW1[0], xvO.y);
    MIXLO(xa_y1, XW1[1], xvO.z); MIXHI(xa_y1, XW1[1], xvO.w);

    // hidden dots: 4 accs x 32 K = 128 fma_mix, 4 independent chains
    float a_x0 = bh0, a_y0 = bh0, a_x1 = bh1, a_y1 = bh1;
#pragma unroll
    for (int c = 0; c < 8; ++c) {
      MIXQ(a_x0, W0, c, hx[c]);
      MIXQ(a_y0, W0, c, hy[c]);
      MIXQ(a_x1, W1, c, hx[c]);
      MIXQ(a_y1, W1, c, hy[c]);
    }

    // cross-group exchanges (both directions useful per swap)
    const float e0 = __shfl_xor(a_y0, 32, 64);   // grp0 gets nhA | grp1 gets hrB
    const float e1 = __shfl_xor(xa_y0, 32, 64);  // grp0 gets xnA | grp1 gets xrB
    const float e2 = __shfl_xor(a_y1, 32, 64);   // grp0 gets projA | grp1 gets hzB
    const float e3 = __shfl_xor(xa_y1, 32, 64);  // (junk) | grp1 gets xzB

    // assemble final-batch gate pre-activations (cndmask selects, uniform flow)
    const float rp = (grp ? e1 : xa_x0) + (grp ? e0 : a_x0);
    const float zp = (grp ? e3 : xa_x1) + (grp ? e2 : a_x1);
    const float nh = grp ? a_x0 : e0;
    const float xn = grp ? xa_x0 : e1;
    const float pv = grp ? a_x1 : e2;

    // proj store: pv is proj(h_t) = out[t-1] (full K=32 dot, no butterfly)
    if (t > 0 && j < 4) outF[(t - 1) * SS + j] = pv + bp;
    if (t == TT) break;

    const float r  = fast_sigm(rp);
    const float z  = fast_sigm(zp);
    const float n  = fast_tanh(fmaf(r, nh, xn));
    const float hnew = fmaf(z, h_self - n, n);   // (1-z)n + z h
    h_self = hnew;
    lrowF[j] = hnew;  // 2 rows x 32 lanes -> 2-way bank alias (free, m136)
  }

  // hn output: [1, B, H]; each lane owns (bF, j)
  out[(size_t)BB * TT * SS + (size_t)bF * HH + j] = h_self;
}

extern "C" void kernel_launch(void* const* d_in, const int* in_sizes, int n_in,
                              void* d_out, int out_size, void* d_ws, size_t ws_size,
                              hipStream_t stream) {
  const float* x      = (const float*)d_in[0];
  const float* h0     = (const float*)d_in[1];
  const float* w_ih   = (const float*)d_in[2];
  const float* w_hh   = (const float*)d_in[3];
  const float* b_ih   = (const float*)d_in[4];
  const float* b_hh   = (const float*)d_in[5];
  const float* w_proj = (const float*)d_in[6];
  const float* b_proj = (const float*)d_in[7];
  float* out = (float*)d_out;

  dim3 grid(BB / 8), block(256);
  hipLaunchKernelGGL(gru_kernel, grid, block, 0, stream,
                     x, h0, w_ih, w_hh, b_ih, b_hh, w_proj, b_proj, out);
}